// Round 6
// baseline (692.212 us; speedup 1.0000x reference)
//
#include <hip/hip_runtime.h>
#include <stdint.h>

#define DD 2048   // hidden
#define HH 1408   // intermediate
#define EE 8      // experts
#define TT 4096   // tokens (B*S)

#define BM 128
#define BK 64
#define MAXBLK 72   // >= max live m-blocks = 64 + 8 rounding
#define NB1 22      // HH / 64 h-cols per block
#define NB2 16      // DD / 128 out-cols per block
#define NW8 2883584 // EE*HH*DD/8

using floatx4 = __attribute__((ext_vector_type(4))) float;
using bf16x8  = __attribute__((ext_vector_type(8))) __bf16;

// round-half-up fp32->bf16 pair pack: result = (bf(b)<<16)|bf(a)
__device__ __forceinline__ unsigned int pack_bf16(float a, float b) {
    unsigned int ua = __float_as_uint(a) + 0x8000u;
    unsigned int ub = __float_as_uint(b) + 0x8000u;
    return __builtin_amdgcn_perm(ub, ua, 0x07060302u);
}
__device__ __forceinline__ unsigned short f2bf(float a) {
    return (unsigned short)((__float_as_uint(a) + 0x8000u) >> 16);
}

// async global->LDS, 16B per lane; LDS dest = base + lane*16 (wave-uniform base)
__device__ __forceinline__ void gld16(const unsigned short* g, unsigned short* l) {
    __builtin_amdgcn_global_load_lds(
        (__attribute__((address_space(1))) void*)g,
        (__attribute__((address_space(3))) void*)l, 16, 0, 0);
}

// bijective XCD swizzle over [0, live): consecutive work ids land on one XCD
__device__ __forceinline__ int xcd_swz(int bid, int live) {
    int xcd = bid & 7, pos = bid >> 3;
    int q = live >> 3, r = live & 7;
    return (xcd < r ? xcd * (q + 1) : r * (q + 1) + (xcd - r) * q) + pos;
}

// ---------------- prep: zero counts/cursors + fp32->bf16 convert of W1/W3/W2 ----------------
__global__ __launch_bounds__(256) void k_prep(const float* __restrict__ W1,
                                              const float* __restrict__ W3,
                                              const float* __restrict__ W2,
                                              unsigned short* __restrict__ W1b,
                                              unsigned short* __restrict__ W3b,
                                              unsigned short* __restrict__ W2b,
                                              int* __restrict__ counts,
                                              int* __restrict__ cursor) {
    if (blockIdx.x == 0 && threadIdx.x < 16) {
        if (threadIdx.x < 8) counts[threadIdx.x] = 0;
        else                 cursor[threadIdx.x - 8] = 0;
    }
    int i = blockIdx.x * 256 + threadIdx.x;
    if (i >= 3 * NW8) return;
    const float* s; unsigned short* d; int off;
    if (i < NW8)          { s = W1; d = W1b; off = i; }
    else if (i < 2 * NW8) { s = W3; d = W3b; off = i - NW8; }
    else                  { s = W2; d = W2b; off = i - 2 * NW8; }
    const float4* s4 = (const float4*)s + (size_t)off * 2;
    float4 a = s4[0], b = s4[1];
    uint4 o;
    o.x = pack_bf16(a.x, a.y); o.y = pack_bf16(a.z, a.w);
    o.z = pack_bf16(b.x, b.y); o.w = pack_bf16(b.z, b.w);
    *(uint4*)(d + (size_t)off * 8) = o;
}

// ---------------- gate: logits/softmax/top-2 + X->bf16 row + residual row ----------------
__global__ __launch_bounds__(256) void k_gate(const float* __restrict__ x,
                                              const float* __restrict__ Wg,
                                              unsigned short* __restrict__ Xb,
                                              float* __restrict__ out,
                                              int* __restrict__ topk_i,
                                              float* __restrict__ topk_w,
                                              int* __restrict__ counts) {
    const int t = blockIdx.x;
    const int tid = threadIdx.x;
    const float4* xr = (const float4*)(x + (size_t)t * DD);
    float4* orow = (float4*)(out + (size_t)t * DD);
    uint2* xbrow = (uint2*)(Xb + (size_t)t * DD);
    const float4* wg4 = (const float4*)Wg;
    float p[EE];
#pragma unroll
    for (int e = 0; e < EE; ++e) p[e] = 0.f;
#pragma unroll
    for (int it = 0; it < (DD / 4) / 256; ++it) {
        int d4 = it * 256 + tid;
        float4 xv = xr[d4];
        orow[d4] = xv;                                // residual init: out = x
        uint2 pk;
        pk.x = pack_bf16(xv.x, xv.y);
        pk.y = pack_bf16(xv.z, xv.w);
        xbrow[d4] = pk;                               // bf16 activation row
#pragma unroll
        for (int e = 0; e < EE; ++e) {
            float4 wv = wg4[e * (DD / 4) + d4];
            p[e] += xv.x * wv.x + xv.y * wv.y + xv.z * wv.z + xv.w * wv.w;
        }
    }
#pragma unroll
    for (int e = 0; e < EE; ++e) {
#pragma unroll
        for (int off = 32; off; off >>= 1) p[e] += __shfl_xor(p[e], off);
    }
    __shared__ float red[4][EE];
    const int wave = tid >> 6, lane = tid & 63;
    if (lane == 0) {
#pragma unroll
        for (int e = 0; e < EE; ++e) red[wave][e] = p[e];
    }
    __syncthreads();
    if (tid == 0) {
        float lg[EE];
#pragma unroll
        for (int e = 0; e < EE; ++e) lg[e] = red[0][e] + red[1][e] + red[2][e] + red[3][e];
        float mx = lg[0];
#pragma unroll
        for (int e = 1; e < EE; ++e) mx = fmaxf(mx, lg[e]);
        float den = 0.f, pr[EE];
#pragma unroll
        for (int e = 0; e < EE; ++e) { pr[e] = __expf(lg[e] - mx); den += pr[e]; }
        float inv = 1.f / den;
#pragma unroll
        for (int e = 0; e < EE; ++e) pr[e] *= inv;
        int i0 = 0; float v0 = pr[0];
#pragma unroll
        for (int e = 1; e < EE; ++e) if (pr[e] > v0) { v0 = pr[e]; i0 = e; }
        int i1 = -1; float v1 = -1.f;
#pragma unroll
        for (int e = 0; e < EE; ++e) if (e != i0 && pr[e] > v1) { v1 = pr[e]; i1 = e; }
        topk_i[t * 2 + 0] = i0; topk_i[t * 2 + 1] = i1;
        topk_w[t * 2 + 0] = v0; topk_w[t * 2 + 1] = v1;
        atomicAdd(&counts[i0], 1);
        atomicAdd(&counts[i1], 1);
    }
}

// ---------------- scan + live-block table (BM=128 blocks) ----------------
__global__ void k_scan(const int* __restrict__ counts, int* __restrict__ offs,
                       int* __restrict__ blk_e, int* __restrict__ blk_m,
                       int* __restrict__ nblk) {
    if (threadIdx.x == 0) {
        int s = 0, nb = 0;
        for (int e = 0; e < EE; ++e) {
            offs[e] = s;
            int c = counts[e];
            for (int m = 0; m < c; m += BM) { blk_e[nb] = e; blk_m[nb] = m; ++nb; }
            s += c;
        }
        *nblk = nb;
        for (int i = nb; i < MAXBLK; ++i) { blk_e[i] = 0; blk_m[i] = 0; }
    }
}

// ---------------- compact ----------------
__global__ __launch_bounds__(256) void k_compact(const int* __restrict__ topk_i,
                                                 const float* __restrict__ topk_w,
                                                 const int* __restrict__ offs,
                                                 int* __restrict__ cursor,
                                                 int* __restrict__ tok_id,
                                                 float* __restrict__ tok_w) {
    const int t = blockIdx.x * 256 + threadIdx.x;
    if (t >= TT) return;
#pragma unroll
    for (int k = 0; k < 2; ++k) {
        int e = topk_i[t * 2 + k];
        int slot = atomicAdd(&cursor[e], 1);
        int p = offs[e] + slot;
        tok_id[p] = t;
        tok_w[p] = topk_w[t * 2 + k];
    }
}

// ---------------- gemm1: h = silu(X@W1^T) * (X@W3^T) ----------------
// 128x128 tile (B-tile = W1/W3 interleaved in 16-row groups), BK=64,
// 4 waves of 64x64. Depth-2 pipelined: double-buffered LDS, raw barriers,
// counted vmcnt(8) at the flip -> next-next tile's loads stay in flight.
__global__ __launch_bounds__(256, 2) void k_gemm1(const unsigned short* __restrict__ Xb,
                                                  const unsigned short* __restrict__ W1b,
                                                  const unsigned short* __restrict__ W3b,
                                                  const int* __restrict__ counts,
                                                  const int* __restrict__ offs,
                                                  const int* __restrict__ blk_e,
                                                  const int* __restrict__ blk_m,
                                                  const int* __restrict__ nblk,
                                                  const int* __restrict__ tok_id,
                                                  unsigned short* __restrict__ hbuf) {
    const int live = *nblk * NB1;
    int bid = blockIdx.x;
    if (bid >= live) return;
    bid = xcd_swz(bid, live);
    const int b   = bid / NB1;
    const int e   = blk_e[b];
    const int m0  = blk_m[b];
    const int cnt = counts[e];
    const int n0  = (bid % NB1) * 64;    // h-col base (64 h-cols per block)
    const int seg = offs[e];
    const int tid = threadIdx.x;

    __shared__ __align__(16) unsigned short Xs[2][BM * 64];   // 2 x 16 KB
    __shared__ __align__(16) unsigned short Bs[2][BM * 64];   // 2 x 16 KB (W1/W3 interleaved)
    __shared__ int ids[BM];

    if (tid < BM) ids[tid] = tok_id[seg + min(m0 + tid, cnt - 1)];
    __syncthreads();

    const int lane = tid & 63, wave = tid >> 6;
    const int lr = lane >> 3, lc = lane & 7;       // staging: row-in-8, chunk slot
    const int quad = lane >> 4, l16 = lane & 15;
    const int wm = wave >> 1, wn = wave & 1;       // 2M x 2N wave grid

    // A staging pointers: 4 x (8 rows), rows rl = wave*32 + j*8 + lr
    const unsigned short* xp[4];
#pragma unroll
    for (int j = 0; j < 4; ++j) {
        int rl = wave * 32 + j * 8 + lr;
        xp[j] = Xb + (size_t)ids[rl] * DD + (lc ^ lr) * 8;
    }
    // B staging: wave w owns 16-row groups {2w,2w+1}: W1 (j=0,1) / W3 (j=2,3)
    const unsigned short* bpp[4];
#pragma unroll
    for (int j = 0; j < 4; ++j) {
        const unsigned short* base = (j < 2) ? W1b : W3b;
        int row = n0 + wave * 16 + (j & 1) * 8 + lr;
        bpp[j] = base + ((size_t)e * HH + row) * DD + (lc ^ lr) * 8;
    }

    floatx4 acc[4][4];
#pragma unroll
    for (int i = 0; i < 4; ++i)
#pragma unroll
        for (int j = 0; j < 4; ++j) acc[i][j] = (floatx4)(0.f);

    auto stage = [&](int buf, int k0) {
#pragma unroll
        for (int j = 0; j < 4; ++j)
            gld16(xp[j] + k0, &Xs[buf][(wave * 32 + j * 8) * 64]);
#pragma unroll
        for (int j = 0; j < 4; ++j)
            gld16(bpp[j] + k0, &Bs[buf][(wave * 32 + j * 8) * 64]);
    };

    const int NT = DD / BK;   // 32 K-tiles
    stage(0, 0);              // 8 loads -> buf0
    stage(1, BK);             // 8 loads -> buf1
    asm volatile("s_waitcnt vmcnt(8)" ::: "memory");   // buf0 complete
    __builtin_amdgcn_s_barrier();
    __builtin_amdgcn_sched_barrier(0);

    int cur = 0;
    for (int t = 0; t < NT; ++t) {
        bf16x8 a[4][2], bb[4][2];
#pragma unroll
        for (int kk = 0; kk < 2; ++kk) {
#pragma unroll
            for (int mf = 0; mf < 4; ++mf) {
                int r = wm * 64 + mf * 16 + l16;
                int s = (quad + kk * 4) ^ (r & 7);
                a[mf][kk] = *(const bf16x8*)&Xs[cur][r * 64 + s * 8];
            }
#pragma unroll
            for (int nf = 0; nf < 4; ++nf) {
                int r = wn * 64 + nf * 16 + l16;
                int s = (quad + kk * 4) ^ (r & 7);
                bb[nf][kk] = *(const bf16x8*)&Bs[cur][r * 64 + s * 8];
            }
        }
        asm volatile("s_waitcnt lgkmcnt(0)" ::: "memory");  // my reads done
        __builtin_amdgcn_sched_barrier(0);                  // rule 18: pin MFMA below
        __builtin_amdgcn_s_barrier();                       // ALL waves done reading cur
        __builtin_amdgcn_sched_barrier(0);
        if (t + 2 < NT) stage(cur, (t + 2) * BK);           // overwrite cur: safe now
        __builtin_amdgcn_s_setprio(1);
#pragma unroll
        for (int kk = 0; kk < 2; ++kk)
#pragma unroll
            for (int mf = 0; mf < 4; ++mf)
#pragma unroll
                for (int nf = 0; nf < 4; ++nf)
                    acc[mf][nf] = __builtin_amdgcn_mfma_f32_16x16x32_bf16(a[mf][kk], bb[nf][kk], acc[mf][nf], 0, 0, 0);
        __builtin_amdgcn_s_setprio(0);
        if (t + 2 < NT) asm volatile("s_waitcnt vmcnt(8)" ::: "memory");  // t+1's 8 done, t+2's fly on
        else            asm volatile("s_waitcnt vmcnt(0)" ::: "memory");  // tail drain
        __builtin_amdgcn_s_barrier();                       // next buffer visible to all
        __builtin_amdgcn_sched_barrier(0);
        cur ^= 1;
    }
    // nf 0/1 -> c1/c3 of h-cols n0+wn*32, nf 2/3 -> c1/c3 of +16
#pragma unroll
    for (int mf = 0; mf < 4; ++mf)
#pragma unroll
        for (int reg = 0; reg < 4; ++reg) {
            int m = wm * 64 + mf * 16 + quad * 4 + reg;
            if (m0 + m < cnt) {
                size_t row = (size_t)(seg + m0 + m) * HH + n0 + wn * 32;
                float c1a = acc[mf][0][reg], c3a = acc[mf][1][reg];
                float c1b = acc[mf][2][reg], c3b = acc[mf][3][reg];
                float hva = (c1a / (1.f + __expf(-c1a))) * c3a;
                float hvb = (c1b / (1.f + __expf(-c1b))) * c3b;
                hbuf[row + l16]      = f2bf(hva);
                hbuf[row + 16 + l16] = f2bf(hvb);
            }
        }
}

// ---------------- gemm2: out += w * (h @ W2^T), same pipelined 128x128 shape ----------------
__global__ __launch_bounds__(256, 2) void k_gemm2(const unsigned short* __restrict__ hbuf,
                                                  const unsigned short* __restrict__ W2b,
                                                  const int* __restrict__ counts,
                                                  const int* __restrict__ offs,
                                                  const int* __restrict__ blk_e,
                                                  const int* __restrict__ blk_m,
                                                  const int* __restrict__ nblk,
                                                  const int* __restrict__ tok_id,
                                                  const float* __restrict__ tok_w,
                                                  float* __restrict__ out) {
    const int live = *nblk * NB2;
    int bid = blockIdx.x;
    if (bid >= live) return;
    bid = xcd_swz(bid, live);
    const int b   = bid / NB2;
    const int e   = blk_e[b];
    const int m0  = blk_m[b];
    const int cnt = counts[e];
    const int n0  = (bid % NB2) * 128;   // out-col base over D
    const int seg = offs[e];
    const int tid = threadIdx.x;

    __shared__ __align__(16) unsigned short As[2][BM * 64];   // 2 x 16 KB
    __shared__ __align__(16) unsigned short Bs[2][BM * 64];   // 2 x 16 KB
    __shared__ int ids[BM];
    __shared__ float wts[BM];

    if (tid < BM) {
        int rc = min(m0 + tid, cnt - 1);
        ids[tid] = tok_id[seg + rc];
        wts[tid] = tok_w[seg + rc];
    }
    __syncthreads();

    const int lane = tid & 63, wave = tid >> 6;
    const int lr = lane >> 3, lc = lane & 7;
    const int quad = lane >> 4, l16 = lane & 15;
    const int wm = wave >> 1, wn = wave & 1;

    const unsigned short* ap[4];
#pragma unroll
    for (int j = 0; j < 4; ++j) {
        int rl = wave * 32 + j * 8 + lr;
        ap[j] = hbuf + (size_t)(seg + min(m0 + rl, cnt - 1)) * HH + (lc ^ lr) * 8;
    }
    const unsigned short* bp[4];
#pragma unroll
    for (int j = 0; j < 4; ++j) {
        int row = n0 + wave * 32 + j * 8 + lr;
        bp[j] = W2b + ((size_t)e * DD + row) * HH + (lc ^ lr) * 8;
    }

    floatx4 acc[4][4];
#pragma unroll
    for (int i = 0; i < 4; ++i)
#pragma unroll
        for (int j = 0; j < 4; ++j) acc[i][j] = (floatx4)(0.f);

    auto stage = [&](int buf, int k0) {
#pragma unroll
        for (int j = 0; j < 4; ++j)
            gld16(ap[j] + k0, &As[buf][(wave * 32 + j * 8) * 64]);
#pragma unroll
        for (int j = 0; j < 4; ++j)
            gld16(bp[j] + k0, &Bs[buf][(wave * 32 + j * 8) * 64]);
    };

    const int NT = HH / BK;   // 22 K-tiles
    stage(0, 0);
    stage(1, BK);
    asm volatile("s_waitcnt vmcnt(8)" ::: "memory");
    __builtin_amdgcn_s_barrier();
    __builtin_amdgcn_sched_barrier(0);

    int cur = 0;
    for (int t = 0; t < NT; ++t) {
        bf16x8 a[4][2], bb[4][2];
#pragma unroll
        for (int kk = 0; kk < 2; ++kk) {
#pragma unroll
            for (int mf = 0; mf < 4; ++mf) {
                int r = wm * 64 + mf * 16 + l16;
                int s = (quad + kk * 4) ^ (r & 7);
                a[mf][kk] = *(const bf16x8*)&As[cur][r * 64 + s * 8];
            }
#pragma unroll
            for (int nf = 0; nf < 4; ++nf) {
                int r = wn * 64 + nf * 16 + l16;
                int s = (quad + kk * 4) ^ (r & 7);
                bb[nf][kk] = *(const bf16x8*)&Bs[cur][r * 64 + s * 8];
            }
        }
        asm volatile("s_waitcnt lgkmcnt(0)" ::: "memory");
        __builtin_amdgcn_sched_barrier(0);
        __builtin_amdgcn_s_barrier();
        __builtin_amdgcn_sched_barrier(0);
        if (t + 2 < NT) stage(cur, (t + 2) * BK);
        __builtin_amdgcn_s_setprio(1);
#pragma unroll
        for (int kk = 0; kk < 2; ++kk)
#pragma unroll
            for (int mf = 0; mf < 4; ++mf)
#pragma unroll
                for (int nf = 0; nf < 4; ++nf)
                    acc[mf][nf] = __builtin_amdgcn_mfma_f32_16x16x32_bf16(a[mf][kk], bb[nf][kk], acc[mf][nf], 0, 0, 0);
        __builtin_amdgcn_s_setprio(0);
        if (t + 2 < NT) asm volatile("s_waitcnt vmcnt(8)" ::: "memory");
        else            asm volatile("s_waitcnt vmcnt(0)" ::: "memory");
        __builtin_amdgcn_s_barrier();
        __builtin_amdgcn_sched_barrier(0);
        cur ^= 1;
    }
#pragma unroll
    for (int mf = 0; mf < 4; ++mf)
#pragma unroll
        for (int reg = 0; reg < 4; ++reg) {
            int m = wm * 64 + mf * 16 + quad * 4 + reg;
            if (m0 + m < cnt) {
                int token = ids[m];
                float w = wts[m];
                float* orow = out + (size_t)token * DD + n0 + wn * 64;
#pragma unroll
                for (int nf = 0; nf < 4; ++nf)
                    atomicAdd(orow + nf * 16 + l16, w * acc[mf][nf][reg]);
            }
        }
}

extern "C" void kernel_launch(void* const* d_in, const int* in_sizes, int n_in,
                              void* d_out, int out_size, void* d_ws, size_t ws_size,
                              hipStream_t stream) {
    const float* x  = (const float*)d_in[0];
    const float* Wg = (const float*)d_in[1];
    const float* W1 = (const float*)d_in[2];
    const float* W3 = (const float*)d_in[3];
    const float* W2 = (const float*)d_in[4];
    float* out = (float*)d_out;

    int*   counts = (int*)d_ws;
    int*   cursor = counts + 8;
    int*   offs   = cursor + 8;
    int*   blk_e  = offs + 8;
    int*   blk_m  = blk_e + MAXBLK;
    int*   nblk   = blk_m + MAXBLK;
    int*   topk_i = nblk + 8;   // keep alignment slack
    float* topk_w = (float*)(topk_i + 2 * TT);
    int*   tok_id = (int*)(topk_w + 2 * TT);
    float* tok_w  = (float*)(tok_id + 2 * TT);
    unsigned short* hbuf = (unsigned short*)(tok_w + 2 * TT);     // 2T x H bf16
    unsigned short* Xb   = hbuf + (size_t)2 * TT * HH;            // T x D bf16
    unsigned short* W1b  = Xb + (size_t)TT * DD;                  // E x H x D bf16
    unsigned short* W3b  = W1b + (size_t)EE * HH * DD;
    unsigned short* W2b  = W3b + (size_t)EE * HH * DD;            // E x D x H bf16
    // total ws use ~178.4 MB

    k_prep<<<(3 * NW8) / 256, 256, 0, stream>>>(W1, W3, W2, W1b, W3b, W2b, counts, cursor);
    k_gate<<<TT, 256, 0, stream>>>(x, Wg, Xb, out, topk_i, topk_w, counts);
    k_scan<<<1, 64, 0, stream>>>(counts, offs, blk_e, blk_m, nblk);
    k_compact<<<TT / 256, 256, 0, stream>>>(topk_i, topk_w, offs, cursor, tok_id, tok_w);
    k_gemm1<<<MAXBLK * NB1, 256, 0, stream>>>(Xb, W1b, W3b, counts, offs,
                                              blk_e, blk_m, nblk, tok_id, hbuf);
    k_gemm2<<<MAXBLK * NB2, 256, 0, stream>>>(hbuf, W2b, counts, offs,
                                              blk_e, blk_m, nblk, tok_id, tok_w, out);
}

// Round 7
// 678.317 us; speedup vs baseline: 1.0205x; 1.0205x over previous
//
#include <hip/hip_runtime.h>
#include <stdint.h>

#define DD 2048   // hidden
#define HH 1408   // intermediate
#define EE 8      // experts
#define TT 4096   // tokens (B*S)

#define BM 128
#define BK 64
#define MAXBLK 72   // >= max live m-blocks = 64 + 8 rounding
#define NB1 22      // HH / 64 h-cols per block
#define NB2 16      // DD / 128 out-cols per block

using floatx4 = __attribute__((ext_vector_type(4))) float;
using bf16x8  = __attribute__((ext_vector_type(8))) __bf16;

// round-half-up fp32->bf16 pair pack: result = (bf(b)<<16)|bf(a)
__device__ __forceinline__ unsigned int pack_bf16(float a, float b) {
    unsigned int ua = __float_as_uint(a) + 0x8000u;
    unsigned int ub = __float_as_uint(b) + 0x8000u;
    return __builtin_amdgcn_perm(ub, ua, 0x07060302u);
}
__device__ __forceinline__ unsigned short f2bf(float a) {
    return (unsigned short)((__float_as_uint(a) + 0x8000u) >> 16);
}

// async global->LDS, 16B per lane; LDS dest = base + lane*16 (wave-uniform base)
__device__ __forceinline__ void gld16(const unsigned short* g, unsigned short* l) {
    __builtin_amdgcn_global_load_lds(
        (__attribute__((address_space(1))) void*)g,
        (__attribute__((address_space(3))) void*)l, 16, 0, 0);
}

// bijective XCD swizzle over [0, live): consecutive work ids land on one XCD
__device__ __forceinline__ int xcd_swz(int bid, int live) {
    int xcd = bid & 7, pos = bid >> 3;
    int q = live >> 3, r = live & 7;
    return (xcd < r ? xcd * (q + 1) : r * (q + 1) + (xcd - r) * q) + pos;
}

// ---- shared pipeline macros (names resolved in kernel scope) ----
// frag reads from Xs[CUR]/Bs[CUR] into a[][]/bb[][]
#define FRAGS(CUR)                                                                   \
    _Pragma("unroll")                                                                \
    for (int kk = 0; kk < 2; ++kk) {                                                 \
        _Pragma("unroll")                                                            \
        for (int mf = 0; mf < 4; ++mf) {                                             \
            int r = wm * 64 + mf * 16 + l16; int s = (quad + kk * 4) ^ (r & 7);      \
            a[mf][kk] = *(const bf16x8*)&Xs[CUR][r * 64 + s * 8]; }                  \
        _Pragma("unroll")                                                            \
        for (int nf = 0; nf < 4; ++nf) {                                             \
            int r = wn * 64 + nf * 16 + l16; int s = (quad + kk * 4) ^ (r & 7);      \
            bb[nf][kk] = *(const bf16x8*)&Bs[CUR][r * 64 + s * 8]; } }

#define MFMA_CLUSTER                                                                 \
    __builtin_amdgcn_s_setprio(1);                                                   \
    _Pragma("unroll")                                                                \
    for (int kk = 0; kk < 2; ++kk)                                                   \
    { _Pragma("unroll")                                                              \
      for (int mf = 0; mf < 4; ++mf)                                                 \
      { _Pragma("unroll")                                                            \
        for (int nf = 0; nf < 4; ++nf)                                               \
            acc[mf][nf] = __builtin_amdgcn_mfma_f32_16x16x32_bf16(                   \
                a[mf][kk], bb[nf][kk], acc[mf][nf], 0, 0, 0); } }                    \
    __builtin_amdgcn_s_setprio(0);

// fp32 W loads into reg bank P (8 dwordx4)
#define WLOAD(P, K0)                                                                 \
    { _Pragma("unroll")                                                              \
      for (int j = 0; j < 4; ++j) {                                                  \
          const float* s_ = wsrc[j] + (K0);                                          \
          wr[8 * (P) + 2 * j]     = *(const float4*)s_;                              \
          wr[8 * (P) + 2 * j + 1] = *(const float4*)(s_ + 4); } }

// pack bank P -> bf16, ds_write swizzled into Bs[CUR] (image identical to old gld16 path)
#define WWRITE(P, CUR)                                                               \
    { _Pragma("unroll")                                                              \
      for (int j = 0; j < 4; ++j) {                                                  \
          float4 u = wr[8 * (P) + 2 * j], v = wr[8 * (P) + 2 * j + 1];               \
          uint4 o;                                                                   \
          o.x = pack_bf16(u.x, u.y); o.y = pack_bf16(u.z, u.w);                      \
          o.z = pack_bf16(v.x, v.y); o.w = pack_bf16(v.z, v.w);                      \
          int rl = wave * 32 + j * 8 + lr;                                           \
          *(uint4*)&Bs[CUR][rl * 64 + (lc ^ lr) * 8] = o; } }

#define XSTAGE(CUR, K0)                                                              \
    { _Pragma("unroll")                                                              \
      for (int j = 0; j < 4; ++j)                                                    \
          gld16(xp[j] + (K0), &Xs[CUR][(wave * 32 + j * 8) * 64]); }

#define BARMID                                                                       \
    asm volatile("s_waitcnt lgkmcnt(0)" ::: "memory");                               \
    __builtin_amdgcn_sched_barrier(0);                                               \
    __builtin_amdgcn_s_barrier();                                                    \
    __builtin_amdgcn_sched_barrier(0);

#define BAREND(N)                                                                    \
    asm volatile("s_waitcnt vmcnt(" #N ") lgkmcnt(0)" ::: "memory");                 \
    __builtin_amdgcn_sched_barrier(0);                                               \
    __builtin_amdgcn_s_barrier();                                                    \
    __builtin_amdgcn_sched_barrier(0);

// one steady-state iteration: frag-read(t) | bar | write W(t+2), load W(t+4), stage X(t+2) | MFMA | counted bar
#define MAIN_ITER(CUR, P, TT)                                                        \
    FRAGS(CUR)                                                                       \
    BARMID                                                                           \
    WWRITE(P, CUR)                                                                   \
    WLOAD(P, ((TT) + 4) * BK)                                                        \
    XSTAGE(CUR, ((TT) + 2) * BK)                                                     \
    MFMA_CLUSTER                                                                     \
    BAREND(12)

// ---------------- gate: logits/softmax/top-2 + X->bf16 row + residual row ----------------
__global__ __launch_bounds__(256) void k_gate(const float* __restrict__ x,
                                              const float* __restrict__ Wg,
                                              unsigned short* __restrict__ Xb,
                                              float* __restrict__ out,
                                              int* __restrict__ topk_i,
                                              float* __restrict__ topk_w,
                                              int* __restrict__ counts) {
    const int t = blockIdx.x;
    const int tid = threadIdx.x;
    const float4* xr = (const float4*)(x + (size_t)t * DD);
    float4* orow = (float4*)(out + (size_t)t * DD);
    uint2* xbrow = (uint2*)(Xb + (size_t)t * DD);
    const float4* wg4 = (const float4*)Wg;
    float p[EE];
#pragma unroll
    for (int e = 0; e < EE; ++e) p[e] = 0.f;
#pragma unroll
    for (int it = 0; it < (DD / 4) / 256; ++it) {
        int d4 = it * 256 + tid;
        float4 xv = xr[d4];
        orow[d4] = xv;                                // residual init: out = x
        uint2 pk;
        pk.x = pack_bf16(xv.x, xv.y);
        pk.y = pack_bf16(xv.z, xv.w);
        xbrow[d4] = pk;                               // bf16 activation row
#pragma unroll
        for (int e = 0; e < EE; ++e) {
            float4 wv = wg4[e * (DD / 4) + d4];
            p[e] += xv.x * wv.x + xv.y * wv.y + xv.z * wv.z + xv.w * wv.w;
        }
    }
#pragma unroll
    for (int e = 0; e < EE; ++e) {
#pragma unroll
        for (int off = 32; off; off >>= 1) p[e] += __shfl_xor(p[e], off);
    }
    __shared__ float red[4][EE];
    const int wave = tid >> 6, lane = tid & 63;
    if (lane == 0) {
#pragma unroll
        for (int e = 0; e < EE; ++e) red[wave][e] = p[e];
    }
    __syncthreads();
    if (tid == 0) {
        float lg[EE];
#pragma unroll
        for (int e = 0; e < EE; ++e) lg[e] = red[0][e] + red[1][e] + red[2][e] + red[3][e];
        float mx = lg[0];
#pragma unroll
        for (int e = 1; e < EE; ++e) mx = fmaxf(mx, lg[e]);
        float den = 0.f, pr[EE];
#pragma unroll
        for (int e = 0; e < EE; ++e) { pr[e] = __expf(lg[e] - mx); den += pr[e]; }
        float inv = 1.f / den;
#pragma unroll
        for (int e = 0; e < EE; ++e) pr[e] *= inv;
        int i0 = 0; float v0 = pr[0];
#pragma unroll
        for (int e = 1; e < EE; ++e) if (pr[e] > v0) { v0 = pr[e]; i0 = e; }
        int i1 = -1; float v1 = -1.f;
#pragma unroll
        for (int e = 0; e < EE; ++e) if (e != i0 && pr[e] > v1) { v1 = pr[e]; i1 = e; }
        topk_i[t * 2 + 0] = i0; topk_i[t * 2 + 1] = i1;
        topk_w[t * 2 + 0] = v0; topk_w[t * 2 + 1] = v1;
        atomicAdd(&counts[i0], 1);
        atomicAdd(&counts[i1], 1);
    }
}

// ---------------- scan + live-block table (BM=128 blocks) ----------------
__global__ void k_scan(const int* __restrict__ counts, int* __restrict__ offs,
                       int* __restrict__ blk_e, int* __restrict__ blk_m,
                       int* __restrict__ nblk) {
    if (threadIdx.x == 0) {
        int s = 0, nb = 0;
        for (int e = 0; e < EE; ++e) {
            offs[e] = s;
            int c = counts[e];
            for (int m = 0; m < c; m += BM) { blk_e[nb] = e; blk_m[nb] = m; ++nb; }
            s += c;
        }
        *nblk = nb;
        for (int i = nb; i < MAXBLK; ++i) { blk_e[i] = 0; blk_m[i] = 0; }
    }
}

// ---------------- compact ----------------
__global__ __launch_bounds__(256) void k_compact(const int* __restrict__ topk_i,
                                                 const float* __restrict__ topk_w,
                                                 const int* __restrict__ offs,
                                                 int* __restrict__ cursor,
                                                 int* __restrict__ tok_id,
                                                 float* __restrict__ tok_w) {
    const int t = blockIdx.x * 256 + threadIdx.x;
    if (t >= TT) return;
#pragma unroll
    for (int k = 0; k < 2; ++k) {
        int e = topk_i[t * 2 + k];
        int slot = atomicAdd(&cursor[e], 1);
        int p = offs[e] + slot;
        tok_id[p] = t;
        tok_w[p] = topk_w[t * 2 + k];
    }
}

// ---------------- gemm1: h = silu(X@W1^T) * (X@W3^T) ----------------
// 128x128 tile; X staged bf16 via gld16; W1/W3 read fp32 and converted in-staging
// (reg-staged 4 K-steps ahead, 2 banks). Depth-2 LDS dbuf, counted vmcnt(12).
__global__ __launch_bounds__(256, 2) void k_gemm1(const unsigned short* __restrict__ Xb,
                                                  const float* __restrict__ W1f,
                                                  const float* __restrict__ W3f,
                                                  const int* __restrict__ counts,
                                                  const int* __restrict__ offs,
                                                  const int* __restrict__ blk_e,
                                                  const int* __restrict__ blk_m,
                                                  const int* __restrict__ nblk,
                                                  const int* __restrict__ tok_id,
                                                  unsigned short* __restrict__ hbuf) {
    const int live = *nblk * NB1;
    int bid = blockIdx.x;
    if (bid >= live) return;
    bid = xcd_swz(bid, live);
    const int b   = bid / NB1;
    const int e   = blk_e[b];
    const int m0  = blk_m[b];
    const int cnt = counts[e];
    const int n0  = (bid % NB1) * 64;    // h-col base (64 h-cols per block)
    const int seg = offs[e];
    const int tid = threadIdx.x;

    __shared__ __align__(16) unsigned short Xs[2][BM * 64];   // 2 x 16 KB
    __shared__ __align__(16) unsigned short Bs[2][BM * 64];   // 2 x 16 KB (W1/W3 interleaved)
    __shared__ int ids[BM];

    if (tid < BM) ids[tid] = tok_id[seg + min(m0 + tid, cnt - 1)];
    __syncthreads();

    const int lane = tid & 63, wave = tid >> 6;
    const int lr = lane >> 3, lc = lane & 7;       // staging: row-in-8, chunk slot
    const int quad = lane >> 4, l16 = lane & 15;
    const int wm = wave >> 1, wn = wave & 1;       // 2M x 2N wave grid

    // X staging pointers (bf16, pre-swizzled global side as before)
    const unsigned short* xp[4];
#pragma unroll
    for (int j = 0; j < 4; ++j) {
        int rl = wave * 32 + j * 8 + lr;
        xp[j] = Xb + (size_t)ids[rl] * DD + (lc ^ lr) * 8;
    }
    // W fp32 sources (LINEAR chunks; swizzle applied at ds_write instead)
    // LDS rows wave*32 + j*8 + lr hold: j<2 -> W1, j>=2 -> W3, rows n0+wave*16+(j&1)*8+lr
    const float* wsrc[4];
#pragma unroll
    for (int j = 0; j < 4; ++j) {
        const float* base = (j < 2) ? W1f : W3f;
        int row = n0 + wave * 16 + (j & 1) * 8 + lr;
        wsrc[j] = base + ((size_t)e * HH + row) * DD + lc * 8;
    }

    floatx4 acc[4][4];
#pragma unroll
    for (int i = 0; i < 4; ++i)
#pragma unroll
        for (int j = 0; j < 4; ++j) acc[i][j] = (floatx4)(0.f);

    float4 wr[16];               // two W reg banks (P=0 regs 0..7, P=1 regs 8..15)
    bf16x8 a[4][2], bb[4][2];

    const int NT = DD / BK;      // 32
    // ---- prologue: Ws[0]=W(0), Ws[1]=W(1); banks: W(2),W(3) in flight; X(0),X(1) staged ----
    WLOAD(0, 0) WLOAD(1, BK)
    asm volatile("s_waitcnt vmcnt(0)" ::: "memory");
    __builtin_amdgcn_sched_barrier(0);
    WWRITE(0, 0) WWRITE(1, 1)
    WLOAD(0, 2 * BK)
    XSTAGE(0, 0)
    WLOAD(1, 3 * BK)
    XSTAGE(1, BK)
    BAREND(12)                   // drains Wl(2)+Xg(0); leaves Wl(3)+Xg(1) in flight

    // ---- main loop: t = 0 .. NT-5 (even count), 2 iterations per trip ----
    for (int t = 0; t < NT - 4; t += 2) {
        MAIN_ITER(0, 0, t)
        MAIN_ITER(1, 1, t + 1)
    }
    // ---- peeled tail: t = NT-4 .. NT-1 ----
    FRAGS(0) BARMID WWRITE(0, 0) XSTAGE(0, (NT - 2) * BK) MFMA_CLUSTER BAREND(4)
    FRAGS(1) BARMID WWRITE(1, 1) XSTAGE(1, (NT - 1) * BK) MFMA_CLUSTER BAREND(0)
    FRAGS(0) BARMID MFMA_CLUSTER BAREND(0)
    FRAGS(1)
    asm volatile("s_waitcnt lgkmcnt(0)" ::: "memory");
    __builtin_amdgcn_sched_barrier(0);
    MFMA_CLUSTER

    // epilogue: nf 0/1 -> c1/c3 of h-cols n0+wn*32, nf 2/3 -> c1/c3 of +16
#pragma unroll
    for (int mf = 0; mf < 4; ++mf)
#pragma unroll
        for (int reg = 0; reg < 4; ++reg) {
            int m = wm * 64 + mf * 16 + quad * 4 + reg;
            if (m0 + m < cnt) {
                size_t row = (size_t)(seg + m0 + m) * HH + n0 + wn * 32;
                float c1a = acc[mf][0][reg], c3a = acc[mf][1][reg];
                float c1b = acc[mf][2][reg], c3b = acc[mf][3][reg];
                float hva = (c1a / (1.f + __expf(-c1a))) * c3a;
                float hvb = (c1b / (1.f + __expf(-c1b))) * c3b;
                hbuf[row + l16]      = f2bf(hva);
                hbuf[row + 16 + l16] = f2bf(hvb);
            }
        }
}

// ---------------- gemm2: out += w * (h @ W2^T), same pipelined shape, fp32 W2 in-staging ----------------
__global__ __launch_bounds__(256, 2) void k_gemm2(const unsigned short* __restrict__ hbuf,
                                                  const float* __restrict__ W2f,
                                                  const int* __restrict__ counts,
                                                  const int* __restrict__ offs,
                                                  const int* __restrict__ blk_e,
                                                  const int* __restrict__ blk_m,
                                                  const int* __restrict__ nblk,
                                                  const int* __restrict__ tok_id,
                                                  const float* __restrict__ tok_w,
                                                  float* __restrict__ out) {
    const int live = *nblk * NB2;
    int bid = blockIdx.x;
    if (bid >= live) return;
    bid = xcd_swz(bid, live);
    const int b   = bid / NB2;
    const int e   = blk_e[b];
    const int m0  = blk_m[b];
    const int cnt = counts[e];
    const int n0  = (bid % NB2) * 128;   // out-col base over D
    const int seg = offs[e];
    const int tid = threadIdx.x;

    __shared__ __align__(16) unsigned short Xs[2][BM * 64];   // A = hbuf tiles
    __shared__ __align__(16) unsigned short Bs[2][BM * 64];   // B = W2 tiles
    __shared__ int ids[BM];
    __shared__ float wts[BM];

    if (tid < BM) {
        int rc = min(m0 + tid, cnt - 1);
        ids[tid] = tok_id[seg + rc];
        wts[tid] = tok_w[seg + rc];
    }
    __syncthreads();

    const int lane = tid & 63, wave = tid >> 6;
    const int lr = lane >> 3, lc = lane & 7;
    const int quad = lane >> 4, l16 = lane & 15;
    const int wm = wave >> 1, wn = wave & 1;

    const unsigned short* xp[4];
#pragma unroll
    for (int j = 0; j < 4; ++j) {
        int rl = wave * 32 + j * 8 + lr;
        xp[j] = hbuf + (size_t)(seg + min(m0 + rl, cnt - 1)) * HH + (lc ^ lr) * 8;
    }
    const float* wsrc[4];
#pragma unroll
    for (int j = 0; j < 4; ++j) {
        int row = n0 + wave * 32 + j * 8 + lr;
        wsrc[j] = W2f + ((size_t)e * DD + row) * HH + lc * 8;
    }

    floatx4 acc[4][4];
#pragma unroll
    for (int i = 0; i < 4; ++i)
#pragma unroll
        for (int j = 0; j < 4; ++j) acc[i][j] = (floatx4)(0.f);

    float4 wr[16];
    bf16x8 a[4][2], bb[4][2];

    const int NT = HH / BK;      // 22
    WLOAD(0, 0) WLOAD(1, BK)
    asm volatile("s_waitcnt vmcnt(0)" ::: "memory");
    __builtin_amdgcn_sched_barrier(0);
    WWRITE(0, 0) WWRITE(1, 1)
    WLOAD(0, 2 * BK)
    XSTAGE(0, 0)
    WLOAD(1, 3 * BK)
    XSTAGE(1, BK)
    BAREND(12)

    for (int t = 0; t < NT - 4; t += 2) {
        MAIN_ITER(0, 0, t)
        MAIN_ITER(1, 1, t + 1)
    }
    FRAGS(0) BARMID WWRITE(0, 0) XSTAGE(0, (NT - 2) * BK) MFMA_CLUSTER BAREND(4)
    FRAGS(1) BARMID WWRITE(1, 1) XSTAGE(1, (NT - 1) * BK) MFMA_CLUSTER BAREND(0)
    FRAGS(0) BARMID MFMA_CLUSTER BAREND(0)
    FRAGS(1)
    asm volatile("s_waitcnt lgkmcnt(0)" ::: "memory");
    __builtin_amdgcn_sched_barrier(0);
    MFMA_CLUSTER

#pragma unroll
    for (int mf = 0; mf < 4; ++mf)
#pragma unroll
        for (int reg = 0; reg < 4; ++reg) {
            int m = wm * 64 + mf * 16 + quad * 4 + reg;
            if (m0 + m < cnt) {
                int token = ids[m];
                float w = wts[m];
                float* orow = out + (size_t)token * DD + n0 + wn * 64;
#pragma unroll
                for (int nf = 0; nf < 4; ++nf)
                    atomicAdd(orow + nf * 16 + l16, w * acc[mf][nf][reg]);
            }
        }
}

extern "C" void kernel_launch(void* const* d_in, const int* in_sizes, int n_in,
                              void* d_out, int out_size, void* d_ws, size_t ws_size,
                              hipStream_t stream) {
    const float* x  = (const float*)d_in[0];
    const float* Wg = (const float*)d_in[1];
    const float* W1 = (const float*)d_in[2];
    const float* W3 = (const float*)d_in[3];
    const float* W2 = (const float*)d_in[4];
    float* out = (float*)d_out;

    int*   counts = (int*)d_ws;
    int*   cursor = counts + 8;
    int*   offs   = cursor + 8;
    int*   blk_e  = offs + 8;
    int*   blk_m  = blk_e + MAXBLK;
    int*   nblk   = blk_m + MAXBLK;
    int*   topk_i = nblk + 8;   // keep alignment slack
    float* topk_w = (float*)(topk_i + 2 * TT);
    int*   tok_id = (int*)(topk_w + 2 * TT);
    float* tok_w  = (float*)(tok_id + 2 * TT);
    unsigned short* hbuf = (unsigned short*)(tok_w + 2 * TT);     // 2T x H bf16
    unsigned short* Xb   = hbuf + (size_t)2 * TT * HH;            // T x D bf16

    hipMemsetAsync(counts, 0, 16 * sizeof(int), stream);          // counts + cursor
    k_gate<<<TT, 256, 0, stream>>>(x, Wg, Xb, out, topk_i, topk_w, counts);
    k_scan<<<1, 64, 0, stream>>>(counts, offs, blk_e, blk_m, nblk);
    k_compact<<<TT / 256, 256, 0, stream>>>(topk_i, topk_w, offs, cursor, tok_id, tok_w);
    k_gemm1<<<MAXBLK * NB1, 256, 0, stream>>>(Xb, W1, W3, counts, offs,
                                              blk_e, blk_m, nblk, tok_id, hbuf);
    k_gemm2<<<MAXBLK * NB2, 256, 0, stream>>>(hbuf, W2, counts, offs,
                                              blk_e, blk_m, nblk, tok_id, tok_w, out);
}